// Round 11
// baseline (58.983 us; speedup 1.0000x reference)
//
#include <hip/hip_runtime.h>
#include <math.h>

// Problem constants (from reference)
#define M_SLOTS 64
#define E_DIM   64
#define KEY_DIM 64
#define V_DIM   128
#define K_CAT   4
#define S_LEN   200

typedef __attribute__((ext_vector_type(8)))  short short8;
typedef __attribute__((ext_vector_type(16))) float f32x16;

// ---------------- ws layout (float offsets) ----------------
#define OFF_CT     0                          // 4096 ushort = 2048 f  (Ct[m][e] bf16)
#define OFF_BM     2048                       // 64
#define OFF_WBAR   2112                       // 64
#define OFF_BBAR   2176                       // 1
#define OFF_RM0    2240                       // 64
#define OFF_P0     2304                       // 64
#define OFF_WSUM   2368                       // S*M = 12800 (zeroed by k_pre)
#define OFF_EMSUM  (OFF_WSUM + S_LEN*M_SLOTS) // 200 (zeroed, contiguous w/ wsum)
#define OFF_QST    15424                      // S*B ints (102400 @ B=512)
#define OFF_RST    (OFF_QST + S_LEN*512)      // S*B ints
#define OFF_RM     (OFF_RST + S_LEN*512)      // S*M f32, slot-permuted per t

// work-item ranges for k_pre
#define PRE_CT_END   4096
#define PRE_BM_END   4160
#define PRE_WBAR_END 4224
#define PRE_BBAR     4224
#define PRE_RM_BEG   4225
#define PRE_RM_END   4289
#define PRE_Z_BEG    4289
#define PRE_Z_END    (4289 + S_LEN*M_SLOTS + S_LEN)
#define PRE_T_BEG    PRE_Z_END                // then 2*S*B transpose items

// pack two f32 -> bf16 pair, round-to-nearest-even (for MFMA inputs)
__device__ __forceinline__ unsigned pk2rne(float lo, float hi) {
    unsigned ul = __float_as_uint(lo); ul += 0x7fffu + ((ul >> 16) & 1u);
    unsigned uh = __float_as_uint(hi); uh += 0x7fffu + ((uh >> 16) & 1u);
    return __builtin_amdgcn_perm(uh, ul, 0x07060302u);
}
__device__ __forceinline__ unsigned short bf16rne(float f) {
    unsigned u = __float_as_uint(f);
    return (unsigned short)((u + 0x7fffu + ((u >> 16) & 1u)) >> 16);
}
__device__ __forceinline__ short8 as_s8(uint4 u) { return __builtin_bit_cast(short8, u); }

__device__ __forceinline__ void gpcm_store(float th, int q,
                                           const float* __restrict__ alpha_mean,
                                           const float* __restrict__ beta_base,
                                           const float* __restrict__ beta_gaps,
                                           float* __restrict__ out, size_t idx) {
    float a  = __expf(alpha_mean[q]);
    float b0 = beta_base[q];
    float2 g = *reinterpret_cast<const float2*>(&beta_gaps[q * (K_CAT - 2)]);
    float g0 = log1pf(__expf(g.x));
    float g1 = log1pf(__expf(g.y));
    float be1 = b0 + g0;
    float be2 = be1 + g1;
    float z0 = a * (th - b0);
    float z1 = a * (th - be1);
    float z2 = a * (th - be2);
    float c1 = z0, c2 = z0 + z1, c3 = z0 + z1 + z2;
    float cm = fmaxf(fmaxf(0.f, c1), fmaxf(c2, c3));
    float e0 = __expf(0.f - cm), e1 = __expf(c1 - cm), e2 = __expf(c2 - cm), e3 = __expf(c3 - cm);
    float si = __fdividef(1.0f, e0 + e1 + e2 + e3);
    float4 o4 = make_float4(e0 * si, e1 * si, e2 * si, e3 * si);
    *reinterpret_cast<float4*>(&out[idx * K_CAT]) = o4;
}

// Shared MFMA matvec (32x32x16): lane = (h,p); acc[mt][j] = logit for
// m = (j&3) + 8*((j>>2)&3) + 4*h + 32*mt, pair col p.
__device__ __forceinline__ void mfma_logits(
    const float* __restrict__ qrow, const unsigned short* __restrict__ ct,
    const float* __restrict__ bm, int h, int p, f32x16 acc[2])
{
    float4 qf[8];
    #pragma unroll
    for (int s = 0; s < 4; ++s) {
        const float4* src = (const float4*)(qrow + s * 16 + h * 8);
        qf[2 * s]     = src[0];
        qf[2 * s + 1] = src[1];
    }
    uint4 af[8];
    #pragma unroll
    for (int mt = 0; mt < 2; ++mt)
        #pragma unroll
        for (int s = 0; s < 4; ++s)
            af[mt * 4 + s] = *(const uint4*)(ct + (p + 32 * mt) * E_DIM + s * 16 + h * 8);
    #pragma unroll
    for (int mt = 0; mt < 2; ++mt)
        #pragma unroll
        for (int g = 0; g < 4; ++g) {
            float4 v = *(const float4*)(bm + 8 * g + 4 * h + 32 * mt);
            acc[mt][4 * g + 0] = v.x; acc[mt][4 * g + 1] = v.y;
            acc[mt][4 * g + 2] = v.z; acc[mt][4 * g + 3] = v.w;
        }
    #pragma unroll
    for (int s = 0; s < 4; ++s) {
        uint4 bf;
        bf.x = pk2rne(qf[2 * s].x,     qf[2 * s].y);
        bf.y = pk2rne(qf[2 * s].z,     qf[2 * s].w);
        bf.z = pk2rne(qf[2 * s + 1].x, qf[2 * s + 1].y);
        bf.w = pk2rne(qf[2 * s + 1].z, qf[2 * s + 1].w);
        short8 bfr = as_s8(bf);
        acc[0] = __builtin_amdgcn_mfma_f32_32x32x16_bf16(as_s8(af[s]),     bfr, acc[0], 0, 0, 0);
        acc[1] = __builtin_amdgcn_mfma_f32_32x32x16_bf16(as_s8(af[4 + s]), bfr, acc[1], 0, 0, 0);
    }
}

// Precompute Ct bf16, bm, wbar, bbar, rm0, p0; zero wsum/emsum; transpose qs/rs.
__global__ void k_pre(const float* __restrict__ q2k_w, const float* __restrict__ q2k_b,
                      const float* __restrict__ mkeys,
                      const float* __restrict__ ev_w, const float* __restrict__ ev_b,
                      const float* __restrict__ means, const float* __restrict__ logvars,
                      const int* __restrict__ qs, const int* __restrict__ rs,
                      float* __restrict__ ws, int B) {
    int gid = blockIdx.x * blockDim.x + threadIdx.x;
    if (gid < PRE_CT_END) {
        int e = gid >> 6, m = gid & 63;
        float s = 0.f;
        #pragma unroll
        for (int k = 0; k < KEY_DIM; ++k) s = fmaf(q2k_w[e * KEY_DIM + k], mkeys[m * KEY_DIM + k], s);
        ((unsigned short*)ws)[m * E_DIM + e] = bf16rne(s);   // transposed store
    } else if (gid < PRE_BM_END) {
        int m = gid - PRE_CT_END;
        float s = 0.f;
        #pragma unroll
        for (int k = 0; k < KEY_DIM; ++k) s = fmaf(q2k_b[k], mkeys[m * KEY_DIM + k], s);
        ws[OFF_BM + m] = s;
    } else if (gid < PRE_WBAR_END) {
        int e = gid - PRE_BM_END;
        float s = 0.f;
        for (int v = 0; v < V_DIM; ++v) s += ev_w[e * V_DIM + v];
        ws[OFF_WBAR + e] = s * (1.0f / V_DIM);
    } else if (gid == PRE_BBAR) {
        float s = 0.f;
        for (int v = 0; v < V_DIM; ++v) s += ev_b[v];
        ws[OFF_BBAR] = s * (1.0f / V_DIM);
    } else if (gid >= PRE_RM_BEG && gid < PRE_RM_END) {
        int m = gid - PRE_RM_BEG;
        const float4* mr = (const float4*)(means + (size_t)m * V_DIM);
        float s = 0.f;
        #pragma unroll
        for (int i = 0; i < V_DIM / 4; ++i) { float4 v = mr[i]; s += (v.x + v.y) + (v.z + v.w); }
        ws[OFF_RM0 + m] = s * (1.0f / V_DIM);
        ws[OFF_P0 + m]  = __expf(-logvars[(size_t)m * V_DIM]);  // row-uniform by construction
    } else if (gid >= PRE_Z_BEG && gid < PRE_Z_END) {
        ws[OFF_WSUM + (gid - PRE_Z_BEG)] = 0.f;
    } else {
        int i = gid - PRE_T_BEG;
        const int SB = S_LEN * B;
        if (i < SB) {
            int t = i / B, b = i - t * B;
            ((int*)(ws + OFF_QST))[i] = qs[(size_t)b * S_LEN + t];   // coalesced write
        } else if (i < 2 * SB) {
            int j = i - SB;
            int t = j / B, b = j - t * B;
            ((int*)(ws + OFF_RST))[j] = rs[(size_t)b * S_LEN + t];
        }
    }
}

// Stats-only attention: coalesced qsT/rsT first hop, MFMA logits, softmax, fold, atomics.
__global__ __launch_bounds__(256, 3) void k_attn(
    const float* __restrict__ qtab, const float* __restrict__ ws_ro,
    const float* __restrict__ qa_w, const float* __restrict__ qa_b,
    float* __restrict__ wsum, float* __restrict__ emsum,
    int B, float invNQ)
{
    __shared__ float4 lsEv[64];
    const int tid = threadIdx.x, wv = tid >> 6, lane = tid & 63;
    const int h = lane >> 5, p = lane & 31;
    const int t = blockIdx.x;
    const int b = blockIdx.y * 128 + wv * 32 + p;

    const int q = ((const int*)(ws_ro + OFF_QST))[t * B + b];
    const int r = ((const int*)(ws_ro + OFF_RST))[t * B + b];

    if (tid < 64) lsEv[tid] = make_float4(qa_w[tid], qa_w[E_DIM + tid], qa_b[tid],
                                          ws_ro[OFF_WBAR + tid]);
    const float bb = ws_ro[OFF_BBAR];

    f32x16 acc[2];
    mfma_logits(qtab + (size_t)q * E_DIM, (const unsigned short*)ws_ro,
                ws_ro + OFF_BM, h, p, acc);

    // softmax over 64 slots of pair p (half h holds 32)
    float av[32];
    float ssum = 0.f;
    #pragma unroll
    for (int j = 0; j < 16; ++j) { av[j]      = __expf(acc[0][j]); ssum += av[j]; }
    #pragma unroll
    for (int j = 0; j < 16; ++j) { av[16 + j] = __expf(acc[1][j]); ssum += av[16 + j]; }
    ssum += __shfl_xor(ssum, 32);
    const float inv = __fdividef(1.0f, ssum);

    // fold normalized attn over 32 pairs (within half); lane ends with j=lane&31
    #pragma unroll
    for (int j = 0; j < 32; ++j) av[j] *= inv;
    #pragma unroll
    for (int step = 0; step < 5; ++step) {
        const int sh = 1 << step;
        #pragma unroll
        for (int j = 0; j < (32 >> step) / 2; ++j) {
            float p0 = av[2 * j]     + __shfl_xor(av[2 * j], sh);
            float p1 = av[2 * j + 1] + __shfl_xor(av[2 * j + 1], sh);
            av[j] = (lane & sh) ? p1 : p0;
        }
    }
    {
        const int jj = lane & 31;
        const int m = (jj & 3) + 8 * ((jj >> 2) & 3) + 4 * h + 32 * (jj >> 4);
        atomicAdd(&wsum[t * M_SLOTS + m], av[0]);
    }

    __syncthreads();   // lsEv ready

    // evidence scalar
    float qn = (float)q * invNQ;
    float rn = (float)r * (1.0f / (K_CAT - 1));
    float evm = 0.f;
    #pragma unroll 8
    for (int e = 0; e < 32; ++e) {
        float4 pv = lsEv[h * 32 + e];
        float qa = fmaf(qn, pv.x, fmaf(rn, pv.y, pv.z));
        float ez = __expf(2.0f * qa);
        evm = fmaf(__fdividef(ez - 1.0f, ez + 1.0f), pv.w, evm);
    }
    evm += __shfl_xor(evm, 32);
    evm += bb;
    #pragma unroll
    for (int o = 16; o; o >>= 1) evm += __shfl_xor(evm, o);
    if (!lane) atomicAdd(&emsum[t], evm);
}

// rm kernel: block t, lane m. Closed-form prefix, written slot-PERMUTED.
__global__ __launch_bounds__(64) void k_rm(
    const float* __restrict__ ws_ro, float* __restrict__ rm, float invB)
{
    const int t = blockIdx.x, m = threadIdx.x;
    const float* wsum  = ws_ro + OFF_WSUM;
    const float* emsum = ws_ro + OFF_EMSUM;
    float den = ws_ro[OFF_P0 + m];
    float num = den * ws_ro[OFF_RM0 + m];
    int s = 0;
    for (; s + 4 <= t; s += 4) {
        float w0 = wsum[(s + 0) * M_SLOTS + m] * invB;
        float w1 = wsum[(s + 1) * M_SLOTS + m] * invB;
        float w2 = wsum[(s + 2) * M_SLOTS + m] * invB;
        float w3 = wsum[(s + 3) * M_SLOTS + m] * invB;
        num = fmaf(emsum[s + 0] * invB, w0, num); den += w0;
        num = fmaf(emsum[s + 1] * invB, w1, num); den += w1;
        num = fmaf(emsum[s + 2] * invB, w2, num); den += w2;
        num = fmaf(emsum[s + 3] * invB, w3, num); den += w3;
    }
    for (; s < t; ++s) {
        float w = wsum[s * M_SLOTS + m] * invB;
        num = fmaf(emsum[s] * invB, w, num);
        den += w;
    }
    // slot-permuted index: idx = h(m)*32 + mt(m)*16 + j(m)
    const int idx = ((m >> 2) & 1) * 32 + ((m >> 5) & 1) * 16 + (m & 3) + 4 * ((m >> 3) & 3);
    rm[t * M_SLOTS + idx] = num / den;   // state BEFORE update at t
}

// Output: load rm_t (permuted) via LDS, MFMA recompute, softmax, theta dot, GPCM.
__global__ __launch_bounds__(256, 3) void k_out(
    const float* __restrict__ qtab, const float* __restrict__ ws_ro,
    const float* __restrict__ rm,
    const float* __restrict__ alpha_mean, const float* __restrict__ beta_base,
    const float* __restrict__ beta_gaps, float* __restrict__ out, int B)
{
    __shared__ float lsRm[M_SLOTS];
    const int tid = threadIdx.x, wv = tid >> 6, lane = tid & 63;
    const int h = lane >> 5, p = lane & 31;
    const int t = blockIdx.x;
    const int b = blockIdx.y * 128 + wv * 32 + p;

    const int q = ((const int*)(ws_ro + OFF_QST))[t * B + b];
    if (tid < 64) lsRm[tid] = rm[t * M_SLOTS + tid];
    __syncthreads();

    f32x16 acc[2];
    mfma_logits(qtab + (size_t)q * E_DIM, (const unsigned short*)ws_ro,
                ws_ro + OFF_BM, h, p, acc);

    float ssum = 0.f, th = 0.f;
    const float* rmh = lsRm + h * 32;
    #pragma unroll
    for (int j = 0; j < 16; ++j) {
        float e = __expf(acc[0][j]);
        ssum += e;
        th = fmaf(e, rmh[j], th);
    }
    #pragma unroll
    for (int j = 0; j < 16; ++j) {
        float e = __expf(acc[1][j]);
        ssum += e;
        th = fmaf(e, rmh[16 + j], th);
    }
    ssum += __shfl_xor(ssum, 32);
    th   += __shfl_xor(th, 32);
    th = __fdividef(th, ssum);

    if (!h) gpcm_store(th, q, alpha_mean, beta_base, beta_gaps, out, (size_t)b * S_LEN + t);
}

extern "C" void kernel_launch(void* const* d_in, const int* in_sizes, int n_in,
                              void* d_out, int out_size, void* d_ws, size_t ws_size,
                              hipStream_t stream) {
    const float* qtab       = (const float*)d_in[0];
    const float* alpha_mean = (const float*)d_in[1];
    const float* beta_base  = (const float*)d_in[2];
    const float* beta_gaps  = (const float*)d_in[3];
    const float* ab_means   = (const float*)d_in[4];
    const float* ab_logvars = (const float*)d_in[5];
    const float* mkeys      = (const float*)d_in[6];
    const float* q2k_w      = (const float*)d_in[7];
    const float* q2k_b      = (const float*)d_in[8];
    const float* qa_w       = (const float*)d_in[9];
    const float* qa_b       = (const float*)d_in[10];
    const float* ev_w       = (const float*)d_in[11];
    const float* ev_b       = (const float*)d_in[12];
    const int*   qs         = (const int*)d_in[13];
    const int*   rs         = (const int*)d_in[14];
    float* out = (float*)d_out;
    float* ws  = (float*)d_ws;

    const int NQ = in_sizes[1];
    const int S  = S_LEN;
    const int B  = in_sizes[13] / S;   // 512

    float* wsum  = ws + OFF_WSUM;
    float* emsum = ws + OFF_EMSUM;
    float* rm    = ws + OFF_RM;

    const int pre_items = PRE_T_BEG + 2 * S * B;
    k_pre<<<(pre_items + 255) / 256, 256, 0, stream>>>(
        q2k_w, q2k_b, mkeys, ev_w, ev_b, ab_means, ab_logvars, qs, rs, ws, B);

    dim3 g(S, B / 128);
    k_attn<<<g, 256, 0, stream>>>(qtab, ws, qa_w, qa_b, wsum, emsum, B, 1.0f / (float)NQ);

    k_rm<<<S, 64, 0, stream>>>(ws, rm, 1.0f / (float)B);

    k_out<<<g, 256, 0, stream>>>(qtab, ws, rm, alpha_mean, beta_base,
                                 beta_gaps, out, B);
}